// Round 8
// baseline (104.565 us; speedup 1.0000x reference)
//
#include <hip/hip_runtime.h>
#include <math.h>

typedef __bf16 bf16;
typedef __bf16 bf16x8 __attribute__((ext_vector_type(8)));
typedef float  f32x16 __attribute__((ext_vector_type(16)));

#define D_INC 16
#define NODES 32
#define HID   32
#define HS    48
#define WSZ   48
#define NPX   (HS*WSZ)     // 2304
#define H_IN  96
#define W_IN  96
#define N_B   32

#define MP_BLOCKS   1152   // 32*48*4*48 / 256
#define WPRE_BLOCKS 640    // 163840 / 256

// ---------------- Kernel P+W merged (unchanged) ----------------
__global__ __launch_bounds__(256) void pre_kernel(
    const float* __restrict__ x, bf16* __restrict__ Pg,
    const float* __restrict__ S, const float* __restrict__ W1,
    const float* __restrict__ b1, bf16* __restrict__ Wp)
{
    if (blockIdx.x < MP_BLOCKS) {
        int idx = blockIdx.x * 256 + threadIdx.x;   // ((n*48+r)*4+q)*48+c
        int c  = idx % WSZ;
        int t  = idx / WSZ;
        int q  = t & 3;
        int rr = t >> 2;
        int r  = rr % HS;
        int n  = rr / HS;

        const float* xb = x + ((size_t)(n * D_INC + q * 4)) * (H_IN * W_IN);

        float m0 = -INFINITY, m1 = -INFINITY, m2 = -INFINITY, m3 = -INFINITY;
        #pragma unroll
        for (int dr = 0; dr < 3; ++dr) {
            int xr = 2 * r - 1 + dr;
            if (xr < 0) continue;                   // xr <= 95 always
            #pragma unroll
            for (int dc = 0; dc < 3; ++dc) {
                int xc = 2 * c - 1 + dc;
                if (xc < 0) continue;               // xc <= 95 always
                const float* p = xb + xr * W_IN + xc;
                m0 = fmaxf(m0, p[0 * H_IN * W_IN]);
                m1 = fmaxf(m1, p[1 * H_IN * W_IN]);
                m2 = fmaxf(m2, p[2 * H_IN * W_IN]);
                m3 = fmaxf(m3, p[3 * H_IN * W_IN]);
            }
        }
        union { bf16 hh[4]; uint2 u; } v;
        v.hh[0] = (bf16)m0; v.hh[1] = (bf16)m1; v.hh[2] = (bf16)m2; v.hh[3] = (bf16)m3;
        *(uint2*)(Pg + ((size_t)((n * HS + r) * WSZ + c)) * D_INC + q * 4) = v.u;
    } else {
        // Wkron[o][s][qp][h][j] = S[o,d,t]*W1[o,d,h], k = 16s+8qp+j
        // k==144 -> b1[o,h]; k>144 -> 0. Lane-linear for A-fragment loads.
        int idx = (blockIdx.x - MP_BLOCKS) * 256 + threadIdx.x;
        if (idx >= NODES * 10 * 2 * HID * 8) return;
        int j  = idx & 7;
        int h  = (idx >> 3) & 31;
        int qp = (idx >> 8) & 1;
        int os = idx >> 9;
        int s  = os % 10;
        int o  = os / 10;
        int k  = 16 * s + 8 * qp + j;
        float v = 0.f;
        if (k < 144) {
            int t = k >> 4;
            int d = k & 15;
            v = S[(o * D_INC + d) * 9 + t] * W1[(o * D_INC + d) * HID + h];
        } else if (k == 144) {
            v = b1[o * HID + h];
        }
        Wp[idx] = (bf16)v;
    }
}

// ---------------- Kernel G ----------------
// grid (2 half-images, 32 batch, 16 node-pairs); block 256 = 4 waves.
// Block stages a 24-row half-image P tile (41.6 KB, [row][half][col] chunk
// layout -> lane-contiguous 16 B ds_reads, no bank conflicts). Wave holds
// 2 nodes' Wkron A-frags in regs (80 VGPR, from L2) and sweeps 9 px-tiles:
// 10 ds_read_b128 + 20 MFMA + 2 epilogues per tile. A-side LDS traffic = 0.
// R8 fix vs R7: tap base col is halo col c (taps c-1,c,c+1 -> halo c,c+1,c+2),
// NOT c+1 (which read one past the array at c=47,dj=2,row=25,qp=1).
__global__ __launch_bounds__(256, 2) void gemm_kernel(
    const bf16* __restrict__ Pg, const bf16* __restrict__ Wp,
    const float* __restrict__ W2, const float* __restrict__ b2,
    float* __restrict__ out)
{
    // 26 rows x 2 ch-halves x 50 cols, 16 B chunks = 41,600 B
    __shared__ __align__(16) bf16 Pl[26 * 2 * 50 * 8];

    const int hb   = blockIdx.x;      // image half (24 pool rows)
    const int n    = blockIdx.y;
    const int ob   = blockIdx.z * 2;  // node pair
    const int tid  = threadIdx.x;
    const int lane = tid & 63;
    const int w    = tid >> 6;        // 0..3
    const int ln31 = lane & 31;
    const int qp   = lane >> 5;

    const int r0 = hb * 24;           // first pool row of this half

    const uint4 z4 = make_uint4(0u, 0u, 0u, 0u);

    // ---- stage rows r0-1 .. r0+24 (26), cols 0..47 -> halo cols 1..48 ----
    for (int u = tid; u < 26 * 48 * 2; u += 256) {
        int half = u & 1;
        int c    = (u >> 1) % 48;
        int row  = (u >> 1) / 48;
        int pr   = r0 - 1 + row;
        uint4 v  = z4;
        if (pr >= 0 && pr < HS)
            v = *(const uint4*)(Pg + ((size_t)(n * HS + pr) * WSZ + c) * D_INC + half * 8);
        *(uint4*)(Pl + ((row * 2 + half) * 50 + (c + 1)) * 8) = v;
    }
    if (tid < 104) {                  // halo cols 0 and 49 = 0
        int row  = tid >> 2;
        int half = (tid >> 1) & 1;
        int side = tid & 1;
        *(uint4*)(Pl + ((row * 2 + half) * 50 + side * 49) * 8) = z4;
    }
    __syncthreads();

    // ---- per-node register preloads (L2-hot) ----
    bf16x8 Af[2][10];
    #pragma unroll
    for (int e = 0; e < 2; ++e) {
        const bf16* wp = Wp + (size_t)((ob + e) * 10) * 512 + lane * 8;
        #pragma unroll
        for (int s = 0; s < 10; ++s)
            Af[e][s] = *(const bf16x8*)(wp + s * 512);
    }
    float4 w2v[2][4];
    float  bb[2];
    #pragma unroll
    for (int e = 0; e < 2; ++e) {
        const float* w2b = W2 + (ob + e) * HID + 4 * qp;
        w2v[e][0] = *(const float4*)(w2b);
        w2v[e][1] = *(const float4*)(w2b + 8);
        w2v[e][2] = *(const float4*)(w2b + 16);
        w2v[e][3] = *(const float4*)(w2b + 24);
        bb[e] = b2[ob + e];
    }

    const int    p_base   = w * 288 + ln31;                 // wave's first px
    const size_t outbase0 = (size_t)(n * NODES + ob) * NPX + hb * 1152;

    #pragma unroll
    for (int ti = 0; ti < 9; ++ti) {
        const int p  = p_base + ti * 32;    // px in half-image, 0..1151
        const int rl = p / 48;              // local pool row 0..23
        const int c  = p - rl * 48;
        // tap (di,dj) lives at tile row rl+di (chunk stride 100), halo col c+dj
        const int base_ch = (rl * 2 + qp) * 50 + c;

        // B (pixel) fragments: lane = U[k=16s+8qp+j][px], contiguous b128 reads
        bf16x8 Bf[10];
        #pragma unroll
        for (int s = 0; s < 9; ++s) {
            const int di = s / 3, dj = s % 3;        // compile-time tap offsets
            Bf[s] = *(const bf16x8*)(Pl + (base_ch + di * 100 + dj) * 8);
        }
        {
            bf16x8 bias = {};
            if (qp == 0) bias[0] = (bf16)1.0f;       // k==144 constant-1 slot
            Bf[9] = bias;
        }

        f32x16 acc0 = {};
        f32x16 acc1 = {};
        #pragma unroll
        for (int s = 0; s < 10; ++s) {
            acc0 = __builtin_amdgcn_mfma_f32_32x32x16_bf16(Af[0][s], Bf[s], acc0, 0, 0, 0);
            acc1 = __builtin_amdgcn_mfma_f32_32x32x16_bf16(Af[1][s], Bf[s], acc1, 0, 0, 0);
        }

        #pragma unroll
        for (int e = 0; e < 2; ++e) {
            const f32x16 a = e ? acc1 : acc0;
            float part;
            part  = fmaxf(a[0],  0.f) * w2v[e][0].x;
            part  = fmaf(fmaxf(a[1],  0.f), w2v[e][0].y, part);
            part  = fmaf(fmaxf(a[2],  0.f), w2v[e][0].z, part);
            part  = fmaf(fmaxf(a[3],  0.f), w2v[e][0].w, part);
            part  = fmaf(fmaxf(a[4],  0.f), w2v[e][1].x, part);
            part  = fmaf(fmaxf(a[5],  0.f), w2v[e][1].y, part);
            part  = fmaf(fmaxf(a[6],  0.f), w2v[e][1].z, part);
            part  = fmaf(fmaxf(a[7],  0.f), w2v[e][1].w, part);
            part  = fmaf(fmaxf(a[8],  0.f), w2v[e][2].x, part);
            part  = fmaf(fmaxf(a[9],  0.f), w2v[e][2].y, part);
            part  = fmaf(fmaxf(a[10], 0.f), w2v[e][2].z, part);
            part  = fmaf(fmaxf(a[11], 0.f), w2v[e][2].w, part);
            part  = fmaf(fmaxf(a[12], 0.f), w2v[e][3].x, part);
            part  = fmaf(fmaxf(a[13], 0.f), w2v[e][3].y, part);
            part  = fmaf(fmaxf(a[14], 0.f), w2v[e][3].z, part);
            part  = fmaf(fmaxf(a[15], 0.f), w2v[e][3].w, part);
            float tot = part + __shfl_xor(part, 32);
            tot = fmaxf(tot + bb[e], 0.f);
            if (qp == 0)
                out[outbase0 + (size_t)e * NPX + p] = tot;
        }
    }
}

extern "C" void kernel_launch(void* const* d_in, const int* in_sizes, int n_in,
                              void* d_out, int out_size, void* d_ws, size_t ws_size,
                              hipStream_t stream)
{
    const float* x  = (const float*)d_in[0];
    const float* S  = (const float*)d_in[1];
    const float* W1 = (const float*)d_in[2];
    const float* b1 = (const float*)d_in[3];
    const float* W2 = (const float*)d_in[4];
    const float* b2 = (const float*)d_in[5];
    float* out = (float*)d_out;

    bf16* Pg = (bf16*)d_ws;                                   // 2,359,296 B
    bf16* Wp = (bf16*)((char*)d_ws + (size_t)N_B * NPX * D_INC * 2);  // 327,680 B

    pre_kernel<<<MP_BLOCKS + WPRE_BLOCKS, 256, 0, stream>>>(x, Pg, S, W1, b1, Wp);

    dim3 grid(2, N_B, 16);
    gemm_kernel<<<grid, 256, 0, stream>>>(Pg, Wp, W2, b2, out);
}

// Round 9
// 103.620 us; speedup vs baseline: 1.0091x; 1.0091x over previous
//
#include <hip/hip_runtime.h>
#include <math.h>

typedef __bf16 bf16;
typedef __bf16 bf16x8 __attribute__((ext_vector_type(8)));
typedef float  f32x16 __attribute__((ext_vector_type(16)));

#define D_INC 16
#define NODES 32
#define HID   32
#define HS    48
#define WSZ   48
#define NPX   (HS*WSZ)     // 2304
#define H_IN  96
#define W_IN  96
#define N_B   32

#define MP_BLOCKS   768    // 32 n x 4 ch-quads x 6 row-bands
#define WPRE_BLOCKS 640    // 163840 / 256

// ---------------- Kernel P+W merged ----------------
// blocks [0, MP_BLOCKS): LDS-staged maxpool 3x3 s2 p1 -> Pg (N,48,48,16ch) bf16.
//   Block = (n, ch-quad, 8-pool-row band). Stage x rows 16rb-1..16rb+15 x 96c x 4ch
//   fp32 into LDS via dense float4 loads (~25 wave-instrs/block vs ~216 for
//   per-tap scalar loads), then pool from LDS. Row stride 97 breaks the
//   96==0 (mod 32) bank aliasing of stride-2 tap reads.
// blocks [MP_BLOCKS, ...): Wkron precompute (unchanged).
__global__ __launch_bounds__(256) void pre_kernel(
    const float* __restrict__ x, bf16* __restrict__ Pg,
    const float* __restrict__ S, const float* __restrict__ W1,
    const float* __restrict__ b1, bf16* __restrict__ Wp)
{
    __shared__ float Pt[4][17][97];   // 26,384 B

    const int tid = threadIdx.x;

    if (blockIdx.x < MP_BLOCKS) {
        const int b  = blockIdx.x;
        const int rb = b % 6;              // row band: pool rows 8rb..8rb+7
        const int q  = (b / 6) & 3;        // channel quad
        const int n  = b / 24;
        const int R0 = 16 * rb - 1;        // x-row of Pt row 0

        const float* xb = x + (size_t)(n * D_INC + q * 4) * (H_IN * W_IN);

        // ---- stage: 4ch x 17 rows x 24 float4 = 1632 float4 ----
        for (int s = tid; s < 4 * 17 * 24; s += 256) {
            int c4  = s % 24;
            int t2  = s / 24;
            int row = t2 % 17;
            int ch  = t2 / 17;
            int xr  = R0 + row;            // -1 only when rb==0,row==0; max 95
            float4 v = make_float4(-INFINITY, -INFINITY, -INFINITY, -INFINITY);
            if (xr >= 0)
                v = *(const float4*)(xb + (size_t)ch * (H_IN * W_IN) + xr * W_IN + c4 * 4);
            Pt[ch][row][c4 * 4 + 0] = v.x;
            Pt[ch][row][c4 * 4 + 1] = v.y;
            Pt[ch][row][c4 * 4 + 2] = v.z;
            Pt[ch][row][c4 * 4 + 3] = v.w;
        }
        __syncthreads();

        // ---- pool: 384 px (8 rows x 48 cols) x 4 ch; 1-2 px per thread ----
        int px = tid;
        #pragma unroll
        for (int k = 0; k < 2; ++k, px += 256) {
            if (px < 384) {
                int rl = px / 48;          // 0..7
                int c  = px % 48;
                int r  = 8 * rb + rl;      // global pool row
                int row0 = 2 * rl;         // Pt row of x-row 2r-1

                float m[4];
                #pragma unroll
                for (int ch = 0; ch < 4; ++ch) {
                    // dj=0 tap needs the c==0 guard; dj=1,2 always in-bounds
                    int cl = 2 * c - 1;
                    float mm;
                    {
                        float a0 = (cl >= 0) ? Pt[ch][row0 + 0][cl] : -INFINITY;
                        float a1 = (cl >= 0) ? Pt[ch][row0 + 1][cl] : -INFINITY;
                        float a2 = (cl >= 0) ? Pt[ch][row0 + 2][cl] : -INFINITY;
                        mm = fmaxf(fmaxf(a0, a1), a2);
                    }
                    #pragma unroll
                    for (int dj = 1; dj < 3; ++dj) {
                        int cc = 2 * c - 1 + dj;
                        mm = fmaxf(mm, Pt[ch][row0 + 0][cc]);
                        mm = fmaxf(mm, Pt[ch][row0 + 1][cc]);
                        mm = fmaxf(mm, Pt[ch][row0 + 2][cc]);
                    }
                    m[ch] = mm;
                }
                union { bf16 hh[4]; uint2 u; } v;
                v.hh[0] = (bf16)m[0]; v.hh[1] = (bf16)m[1];
                v.hh[2] = (bf16)m[2]; v.hh[3] = (bf16)m[3];
                *(uint2*)(Pg + ((size_t)((n * HS + r) * WSZ + c)) * D_INC + q * 4) = v.u;
            }
        }
    } else {
        // Wkron[o][s][qp][h][j] = S[o,d,t]*W1[o,d,h], k = 16s+8qp+j
        // k==144 -> b1[o,h]; k>144 -> 0. Lane-linear for A-fragment loads.
        int idx = (blockIdx.x - MP_BLOCKS) * 256 + tid;
        if (idx >= NODES * 10 * 2 * HID * 8) return;
        int j  = idx & 7;
        int h  = (idx >> 3) & 31;
        int qp = (idx >> 8) & 1;
        int os = idx >> 9;
        int s  = os % 10;
        int o  = os / 10;
        int k  = 16 * s + 8 * qp + j;
        float v = 0.f;
        if (k < 144) {
            int t = k >> 4;
            int d = k & 15;
            v = S[(o * D_INC + d) * 9 + t] * W1[(o * D_INC + d) * HID + h];
        } else if (k == 144) {
            v = b1[o * HID + h];
        }
        Wp[idx] = (bf16)v;
    }
}

// ---------------- Kernel G: byte-identical to R8 (control variable) ----------------
// grid (2 half-images, 32 batch, 16 node-pairs); block 256 = 4 waves.
__global__ __launch_bounds__(256, 2) void gemm_kernel(
    const bf16* __restrict__ Pg, const bf16* __restrict__ Wp,
    const float* __restrict__ W2, const float* __restrict__ b2,
    float* __restrict__ out)
{
    // 26 rows x 2 ch-halves x 50 cols, 16 B chunks = 41,600 B
    __shared__ __align__(16) bf16 Pl[26 * 2 * 50 * 8];

    const int hb   = blockIdx.x;      // image half (24 pool rows)
    const int n    = blockIdx.y;
    const int ob   = blockIdx.z * 2;  // node pair
    const int tid  = threadIdx.x;
    const int lane = tid & 63;
    const int w    = tid >> 6;        // 0..3
    const int ln31 = lane & 31;
    const int qp   = lane >> 5;

    const int r0 = hb * 24;           // first pool row of this half

    const uint4 z4 = make_uint4(0u, 0u, 0u, 0u);

    // ---- stage rows r0-1 .. r0+24 (26), cols 0..47 -> halo cols 1..48 ----
    for (int u = tid; u < 26 * 48 * 2; u += 256) {
        int half = u & 1;
        int c    = (u >> 1) % 48;
        int row  = (u >> 1) / 48;
        int pr   = r0 - 1 + row;
        uint4 v  = z4;
        if (pr >= 0 && pr < HS)
            v = *(const uint4*)(Pg + ((size_t)(n * HS + pr) * WSZ + c) * D_INC + half * 8);
        *(uint4*)(Pl + ((row * 2 + half) * 50 + (c + 1)) * 8) = v;
    }
    if (tid < 104) {                  // halo cols 0 and 49 = 0
        int row  = tid >> 2;
        int half = (tid >> 1) & 1;
        int side = tid & 1;
        *(uint4*)(Pl + ((row * 2 + half) * 50 + side * 49) * 8) = z4;
    }
    __syncthreads();

    // ---- per-node register preloads (L2-hot) ----
    bf16x8 Af[2][10];
    #pragma unroll
    for (int e = 0; e < 2; ++e) {
        const bf16* wp = Wp + (size_t)((ob + e) * 10) * 512 + lane * 8;
        #pragma unroll
        for (int s = 0; s < 10; ++s)
            Af[e][s] = *(const bf16x8*)(wp + s * 512);
    }
    float4 w2v[2][4];
    float  bb[2];
    #pragma unroll
    for (int e = 0; e < 2; ++e) {
        const float* w2b = W2 + (ob + e) * HID + 4 * qp;
        w2v[e][0] = *(const float4*)(w2b);
        w2v[e][1] = *(const float4*)(w2b + 8);
        w2v[e][2] = *(const float4*)(w2b + 16);
        w2v[e][3] = *(const float4*)(w2b + 24);
        bb[e] = b2[ob + e];
    }

    const int    p_base   = w * 288 + ln31;                 // wave's first px
    const size_t outbase0 = (size_t)(n * NODES + ob) * NPX + hb * 1152;

    #pragma unroll
    for (int ti = 0; ti < 9; ++ti) {
        const int p  = p_base + ti * 32;    // px in half-image, 0..1151
        const int rl = p / 48;              // local pool row 0..23
        const int c  = p - rl * 48;
        // tap (di,dj) lives at tile row rl+di (chunk stride 100), halo col c+dj
        const int base_ch = (rl * 2 + qp) * 50 + c;

        // B (pixel) fragments: lane = U[k=16s+8qp+j][px], contiguous b128 reads
        bf16x8 Bf[10];
        #pragma unroll
        for (int s = 0; s < 9; ++s) {
            const int di = s / 3, dj = s % 3;        // compile-time tap offsets
            Bf[s] = *(const bf16x8*)(Pl + (base_ch + di * 100 + dj) * 8);
        }
        {
            bf16x8 bias = {};
            if (qp == 0) bias[0] = (bf16)1.0f;       // k==144 constant-1 slot
            Bf[9] = bias;
        }

        f32x16 acc0 = {};
        f32x16 acc1 = {};
        #pragma unroll
        for (int s = 0; s < 10; ++s) {
            acc0 = __builtin_amdgcn_mfma_f32_32x32x16_bf16(Af[0][s], Bf[s], acc0, 0, 0, 0);
            acc1 = __builtin_amdgcn_mfma_f32_32x32x16_bf16(Af[1][s], Bf[s], acc1, 0, 0, 0);
        }

        #pragma unroll
        for (int e = 0; e < 2; ++e) {
            const f32x16 a = e ? acc1 : acc0;
            float part;
            part  = fmaxf(a[0],  0.f) * w2v[e][0].x;
            part  = fmaf(fmaxf(a[1],  0.f), w2v[e][0].y, part);
            part  = fmaf(fmaxf(a[2],  0.f), w2v[e][0].z, part);
            part  = fmaf(fmaxf(a[3],  0.f), w2v[e][0].w, part);
            part  = fmaf(fmaxf(a[4],  0.f), w2v[e][1].x, part);
            part  = fmaf(fmaxf(a[5],  0.f), w2v[e][1].y, part);
            part  = fmaf(fmaxf(a[6],  0.f), w2v[e][1].z, part);
            part  = fmaf(fmaxf(a[7],  0.f), w2v[e][1].w, part);
            part  = fmaf(fmaxf(a[8],  0.f), w2v[e][2].x, part);
            part  = fmaf(fmaxf(a[9],  0.f), w2v[e][2].y, part);
            part  = fmaf(fmaxf(a[10], 0.f), w2v[e][2].z, part);
            part  = fmaf(fmaxf(a[11], 0.f), w2v[e][2].w, part);
            part  = fmaf(fmaxf(a[12], 0.f), w2v[e][3].x, part);
            part  = fmaf(fmaxf(a[13], 0.f), w2v[e][3].y, part);
            part  = fmaf(fmaxf(a[14], 0.f), w2v[e][3].z, part);
            part  = fmaf(fmaxf(a[15], 0.f), w2v[e][3].w, part);
            float tot = part + __shfl_xor(part, 32);
            tot = fmaxf(tot + bb[e], 0.f);
            if (qp == 0)
                out[outbase0 + (size_t)e * NPX + p] = tot;
        }
    }
}

extern "C" void kernel_launch(void* const* d_in, const int* in_sizes, int n_in,
                              void* d_out, int out_size, void* d_ws, size_t ws_size,
                              hipStream_t stream)
{
    const float* x  = (const float*)d_in[0];
    const float* S  = (const float*)d_in[1];
    const float* W1 = (const float*)d_in[2];
    const float* b1 = (const float*)d_in[3];
    const float* W2 = (const float*)d_in[4];
    const float* b2 = (const float*)d_in[5];
    float* out = (float*)d_out;

    bf16* Pg = (bf16*)d_ws;                                   // 2,359,296 B
    bf16* Wp = (bf16*)((char*)d_ws + (size_t)N_B * NPX * D_INC * 2);  // 327,680 B

    pre_kernel<<<MP_BLOCKS + WPRE_BLOCKS, 256, 0, stream>>>(x, Pg, S, W1, b1, Wp);

    dim3 grid(2, N_B, 16);
    gemm_kernel<<<grid, 256, 0, stream>>>(Pg, Wp, W2, b2, out);
}